// Round 6
// baseline (740.454 us; speedup 1.0000x reference)
//
#include <hip/hip_runtime.h>
#include <hip/hip_fp16.h>

#define B_ 256
#define T_ 200
#define H_ 256
#define G3 768            // 3*H
#define NV 50001          // V+1

typedef _Float16 half2v __attribute__((ext_vector_type(2)));
typedef _Float16 half4v __attribute__((ext_vector_type(4)));
typedef _Float16 half8v __attribute__((ext_vector_type(8)));
typedef float f32x4 __attribute__((ext_vector_type(4)));

union U32H2 { unsigned int u; half2v h; };

__device__ __forceinline__ float sigmoidf_(float x) {
  return 1.f / (1.f + __expf(-x));
}
__device__ __forceinline__ float tanhf_(float x) {
  float ax = fabsf(x);
  float e = __expf(-2.f * ax);
  float t = (1.f - e) / (1.f + e);
  return copysignf(t, x);
}
__device__ __forceinline__ f32x4 mfma16(half8v a, half8v b, f32x4 c) {
  return __builtin_amdgcn_mfma_f32_16x16x32_f16(a, b, c, 0, 0, 0);
}

// ---- pack w_hh [256][768] fp32 -> MFMA B-fragment-linear fp16:
// frag f = nt*8+kc (nt in [0,48), kc in [0,8)); within frag: lane (64) x 8 halfs.
// half j of lane l of frag (nt,kc) = w_hh[kc*32 + (l>>4)*8 + j][nt*16 + (l&15)].
__global__ __launch_bounds__(256) void pack_whh_frag(
    const float* __restrict__ whh, unsigned int* __restrict__ out) {
  int idx = blockIdx.x * 256 + threadIdx.x;   // 0..98303
  int f = idx >> 8;                           // nt*8+kc
  int rem = idx & 255;
  int lane = rem >> 2;
  int jp = rem & 3;
  int nt = f >> 3, kc = f & 7;
  int col = nt * 16 + (lane & 15);
  int k = kc * 32 + (lane >> 4) * 8 + jp * 2;
  U32H2 u;
  u.h.x = (_Float16)whh[(size_t)k * G3 + col];
  u.h.y = (_Float16)whh[(size_t)(k + 1) * G3 + col];
  out[idx] = u.u;
}

// ---- pack w_ih -> transposed fp16 [768 cols][256 k] (gates_mfma B staging).
__global__ __launch_bounds__(256) void pack_wiht(
    const float* __restrict__ wih, unsigned int* __restrict__ out) {
  int idx = blockIdx.x * 256 + threadIdx.x;   // 0..98303
  int col = idx >> 7;
  int kk = (idx & 127) * 2;
  U32H2 u;
  u.h.x = (_Float16)wih[(size_t)kk * G3 + col];
  u.h.y = (_Float16)wih[(size_t)(kk + 1) * G3 + col];
  out[idx] = u.u;
}

// ---- K1: gates = emb[ids] @ w_ih + b_ih via f16 MFMA (round-3 version:
// writes rec-friendly layout gates[((t*16+bg)*768+col)*16+ri], verified).
__global__ __launch_bounds__(512) void gates_mfma(
    const int* __restrict__ ids, const float* __restrict__ emb,
    const __half* __restrict__ wih_t, const float* __restrict__ b_ih,
    __half* __restrict__ gates) {
  __shared__ __align__(16) _Float16 As[128 * 72];   // [row][k] stride 72
  __shared__ __align__(16) _Float16 Bs[256 * 72];   // [col][k] stride 72
  __shared__ int ids_s[128];
  __shared__ float bs[256];
  const int tid = threadIdx.x;
  const int t = blockIdx.x >> 1;                 // 128-row block within one t
  const int bbase0 = (blockIdx.x & 1) * 128;
  const int c0 = blockIdx.y * 256;
  const int w = tid >> 6, lane = tid & 63;
  const int wm = w >> 2, wn = w & 3;
  const int lr = lane & 15, lk = lane >> 4;

  if (tid < 128) ids_s[tid] = ids[(bbase0 + tid) * T_ + t];
  if (tid < 256) bs[tid] = b_ih[c0 + tid];
  __syncthreads();

  f32x4 acc[4][4];
#pragma unroll
  for (int i = 0; i < 4; ++i)
#pragma unroll
    for (int j = 0; j < 4; ++j) acc[i][j] = (f32x4){0.f, 0.f, 0.f, 0.f};

  for (int c = 0; c < 4; ++c) {
    const int kc = c * 64;
#pragma unroll
    for (int r4 = 0; r4 < 4; ++r4) {
      int q = tid + r4 * 512;
      int row = q >> 4;
      int kk = (q & 15) * 4;
      const float4 v = *(const float4*)&emb[(size_t)ids_s[row] * H_ + kc + kk];
      half4v hv = {(_Float16)v.x, (_Float16)v.y, (_Float16)v.z, (_Float16)v.w};
      *(half4v*)&As[row * 72 + kk] = hv;
    }
#pragma unroll
    for (int r4 = 0; r4 < 4; ++r4) {
      int q = tid + r4 * 512;
      int col = q >> 3;
      int cc = q & 7;
      uint4 v = *(const uint4*)((const unsigned short*)wih_t +
                                (size_t)(c0 + col) * H_ + kc + cc * 8);
      *(uint4*)&Bs[col * 72 + cc * 8] = v;
    }
    __syncthreads();
#pragma unroll
    for (int ks = 0; ks < 2; ++ks) {
      half8v af[4], bf[4];
#pragma unroll
      for (int i = 0; i < 4; ++i)
        af[i] = *(const half8v*)&As[(wm * 64 + i * 16 + lr) * 72 + ks * 32 + lk * 8];
#pragma unroll
      for (int j = 0; j < 4; ++j)
        bf[j] = *(const half8v*)&Bs[(wn * 64 + j * 16 + lr) * 72 + ks * 32 + lk * 8];
#pragma unroll
      for (int i = 0; i < 4; ++i)
#pragma unroll
        for (int j = 0; j < 4; ++j)
          acc[i][j] = mfma16(af[i], bf[j], acc[i][j]);
    }
    __syncthreads();
  }
  const int bgb = (bbase0 + wm * 64) >> 4;
#pragma unroll
  for (int j = 0; j < 4; ++j) {
    const int col = c0 + wn * 64 + j * 16 + lr;
    const float bj = bs[wn * 64 + j * 16 + lr];
#pragma unroll
    for (int i = 0; i < 4; ++i) {
      size_t base = ((size_t)((t * 16 + bgb + i) * 768 + col)) * 16 + lk * 4;
      half4v hv = {(_Float16)(acc[i][j][0] + bj), (_Float16)(acc[i][j][1] + bj),
                   (_Float16)(acc[i][j][2] + bj), (_Float16)(acc[i][j][3] + bj)};
      *(half4v*)&gates[base] = hv;
    }
  }
}

// ---- K2: GRU recurrence via MFMA, zero register-resident weights.
// 16 WGs x 512 thr (8 waves); WG owns 16 batch rows. Weights: kc 0..2 in
// LDS (147 KB, staged once), kc 3..7 streamed per step (246 KB through the
// 128 B/cyc VMEM path = the wall, ~2100 cyc/step). Wave w owns col-blocks
// {2w,2w+1} for all 3 gates -> GRU update entirely in registers.
__global__ __launch_bounds__(512) void rec_mfma(
    const int* __restrict__ lens, const unsigned int* __restrict__ whh_f,
    const float* __restrict__ b_hh, const __half* __restrict__ gates,
    float* __restrict__ hfin) {
  __shared__ __align__(16) uint4 Wl[144 * 64];   // 147,456 B: kc 0..2 frags
  __shared__ _Float16 h_lds[16 * 264];           // row stride 528 B (2-way ok)
  const int tid = threadIdx.x;
  const int bg = blockIdx.x;
  const int w = tid >> 6, lane = tid & 63;
  const int lr = lane & 15, lk = lane >> 4;

  const uint4* wf = (const uint4*)whh_f;   // frag (nt,kc): wf[(nt*8+kc)*64+lane]

  // stage kc 0..2 for all 48 nt into LDS slot s = nt*3 + kc
#pragma unroll
  for (int i = 0; i < 18; ++i) {
    int idx = tid + i * 512;          // 0..9215
    int s = idx >> 6;                 // 0..143
    int l = idx & 63;
    int nt = s / 3, kc = s - 3 * nt;
    Wl[s * 64 + l] = wf[(nt * 8 + kc) * 64 + l];
  }
  // zero h state
  for (int i = tid; i < 16 * 132; i += 512) ((unsigned int*)h_lds)[i] = 0;

  int nt_[6];
#pragma unroll
  for (int p = 0; p < 6; ++p) nt_[p] = (p >> 1) * 16 + w * 2 + (p & 1);

  int len_r[4];
#pragma unroll
  for (int r = 0; r < 4; ++r) len_r[r] = lens[bg * 16 + lk * 4 + r];
  int lmax = 0;
  for (int i = 0; i < 16; ++i) lmax = max(lmax, lens[bg * 16 + i]);

  float bhh[6];
  int goff[6];
#pragma unroll
  for (int p = 0; p < 6; ++p) {
    int col = (p >> 1) * 256 + w * 32 + (p & 1) * 16 + lr;
    bhh[p] = b_hh[col];
    goff[p] = col * 16 + lk * 4;
  }
  float h_old[2][4];
#pragma unroll
  for (int cb = 0; cb < 2; ++cb)
#pragma unroll
    for (int r = 0; r < 4; ++r) h_old[cb][r] = 0.f;
  __syncthreads();

  const __half* gbase = gates + (size_t)bg * 12288;
  for (int t = 0; t < lmax; ++t) {
    const __half* gt = gbase + (size_t)t * 196608;   // 16*768*16 halfs/step
    half4v gx[6];
#pragma unroll
    for (int p = 0; p < 6; ++p) gx[p] = *(const half4v*)(gt + goff[p]);

    // prefetch streamed kc=3 fragments
    uint4 sb0[6], sb1[6];
#pragma unroll
    for (int p = 0; p < 6; ++p) sb0[p] = wf[(nt_[p] * 8 + 3) * 64 + lane];

    f32x4 acc[6];
#pragma unroll
    for (int p = 0; p < 6; ++p)
      acc[p] = (f32x4){bhh[p], bhh[p], bhh[p], bhh[p]};

    // LDS-resident kc 0..2
#pragma unroll
    for (int kc = 0; kc < 3; ++kc) {
      half8v a = *(const half8v*)&h_lds[lr * 264 + kc * 32 + lk * 8];
#pragma unroll
      for (int p = 0; p < 6; ++p) {
        half8v b = __builtin_bit_cast(half8v, Wl[(nt_[p] * 3 + kc) * 64 + lane]);
        acc[p] = mfma16(a, b, acc[p]);
      }
    }
    // streamed kc 3..7, double-buffered
#pragma unroll
    for (int kc = 3; kc < 8; ++kc) {
      uint4* cur = (kc & 1) ? sb0 : sb1;
      uint4* nxt = (kc & 1) ? sb1 : sb0;
      if (kc < 7) {
#pragma unroll
        for (int p = 0; p < 6; ++p)
          nxt[p] = wf[(nt_[p] * 8 + kc + 1) * 64 + lane];
      }
      half8v a = *(const half8v*)&h_lds[lr * 264 + kc * 32 + lk * 8];
#pragma unroll
      for (int p = 0; p < 6; ++p)
        acc[p] = mfma16(a, __builtin_bit_cast(half8v, cur[p]), acc[p]);
    }
    // in-register GRU update (lane owns z,r,hh for its 8 (row,col) elems)
#pragma unroll
    for (int cb = 0; cb < 2; ++cb)
#pragma unroll
      for (int r = 0; r < 4; ++r) {
        float z = sigmoidf_((float)gx[0 + cb][r] + acc[0 + cb][r]);
        float rr = sigmoidf_((float)gx[2 + cb][r] + acc[2 + cb][r]);
        float hh = tanhf_((float)gx[4 + cb][r] + rr * acc[4 + cb][r]);
        float hv = z * h_old[cb][r] + (1.f - z) * hh;
        if (t < len_r[r]) h_old[cb][r] = hv;
      }
    __syncthreads();   // all waves finished reading h_lds
#pragma unroll
    for (int cb = 0; cb < 2; ++cb) {
      int colh = w * 32 + cb * 16 + lr;
#pragma unroll
      for (int r = 0; r < 4; ++r)
        h_lds[(lk * 4 + r) * 264 + colh] = (_Float16)h_old[cb][r];
    }
    __syncthreads();
  }
#pragma unroll
  for (int cb = 0; cb < 2; ++cb)
#pragma unroll
    for (int r = 0; r < 4; ++r)
      hfin[(size_t)(bg * 16 + lk * 4 + r) * H_ + w * 32 + cb * 16 + lr] =
          h_old[cb][r];
}

// ---- K3: logits = hfin @ emb^T via hi/lo-split f16 MFMA (round-2, measured).
__global__ __launch_bounds__(512) void logits_mfma(
    const float* __restrict__ hfin, const float* __restrict__ emb,
    float* __restrict__ out) {
  __shared__ __align__(16) _Float16 As[256 * 72];
  __shared__ __align__(16) _Float16 Bs[64 * 72];
  const int tid = threadIdx.x;
  const int n0 = blockIdx.x * 64;
  const int w = tid >> 6, lane = tid & 63;
  const int wm = w >> 1, wn = w & 1;
  const int lr = lane & 15, lk = lane >> 4;

  f32x4 a1[4][2], a2[4][2];
#pragma unroll
  for (int i = 0; i < 4; ++i)
#pragma unroll
    for (int j = 0; j < 2; ++j) {
      a1[i][j] = (f32x4){0.f, 0.f, 0.f, 0.f};
      a2[i][j] = (f32x4){0.f, 0.f, 0.f, 0.f};
    }

  for (int c = 0; c < 8; ++c) {
    const int kc = c * 32;
#pragma unroll
    for (int r4 = 0; r4 < 4; ++r4) {
      int q = tid + r4 * 512;
      int row = q >> 3;
      int kk = (q & 7) * 4;
      float4 v = *(const float4*)&hfin[(size_t)row * H_ + kc + kk];
      half4v hi = {(_Float16)v.x, (_Float16)v.y, (_Float16)v.z, (_Float16)v.w};
      half4v lo = {(_Float16)((v.x - (float)hi.x) * 1024.f),
                   (_Float16)((v.y - (float)hi.y) * 1024.f),
                   (_Float16)((v.z - (float)hi.z) * 1024.f),
                   (_Float16)((v.w - (float)hi.w) * 1024.f)};
      int base = row * 72 + (kk >> 3) * 16 + (kk & 7);
      *(half4v*)&As[base] = hi;
      *(half4v*)&As[base + 8] = lo;
    }
    {
      int col = tid >> 3;
      int kk = (tid & 7) * 4;
      int n = n0 + col;
      float4 v = (n < NV) ? *(const float4*)&emb[(size_t)n * H_ + kc + kk]
                          : make_float4(0.f, 0.f, 0.f, 0.f);
      half4v hi = {(_Float16)v.x, (_Float16)v.y, (_Float16)v.z, (_Float16)v.w};
      half4v lo = {(_Float16)((v.x - (float)hi.x) * 1024.f),
                   (_Float16)((v.y - (float)hi.y) * 1024.f),
                   (_Float16)((v.z - (float)hi.z) * 1024.f),
                   (_Float16)((v.w - (float)hi.w) * 1024.f)};
      int base = col * 72 + (kk >> 3) * 16 + (kk & 7);
      *(half4v*)&Bs[base] = hi;
      *(half4v*)&Bs[base + 8] = lo;
    }
    __syncthreads();
    half8v ah[4], al[4];
#pragma unroll
    for (int i = 0; i < 4; ++i) {
      int base = (wm * 64 + i * 16 + lr) * 72 + lk * 16;
      ah[i] = *(const half8v*)&As[base];
      al[i] = *(const half8v*)&As[base + 8];
    }
#pragma unroll
    for (int j = 0; j < 2; ++j) {
      int base = (wn * 32 + j * 16 + lr) * 72 + lk * 16;
      half8v bh = *(const half8v*)&Bs[base];
      half8v bl = *(const half8v*)&Bs[base + 8];
#pragma unroll
      for (int i = 0; i < 4; ++i) {
        a1[i][j] = mfma16(ah[i], bh, a1[i][j]);
        a2[i][j] = mfma16(ah[i], bl, a2[i][j]);
        a2[i][j] = mfma16(al[i], bh, a2[i][j]);
      }
    }
    __syncthreads();
  }
#pragma unroll
  for (int j = 0; j < 2; ++j) {
    int n = n0 + wn * 32 + j * 16 + lr;
    if (n < NV) {
#pragma unroll
      for (int i = 0; i < 4; ++i) {
        int row = wm * 64 + i * 16 + lk * 4;
#pragma unroll
        for (int r = 0; r < 4; ++r)
          out[(size_t)(row + r) * NV + n] =
              a1[i][j][r] + a2[i][j][r] * (1.f / 1024.f);
      }
    }
  }
}

extern "C" void kernel_launch(void* const* d_in, const int* in_sizes, int n_in,
                              void* d_out, int out_size, void* d_ws, size_t ws_size,
                              hipStream_t stream) {
  const int* ids = (const int*)d_in[0];
  const int* lens = (const int*)d_in[1];
  const float* emb = (const float*)d_in[2];
  const float* w_ih = (const float*)d_in[3];
  const float* w_hh = (const float*)d_in[4];
  const float* b_ih = (const float*)d_in[5];
  const float* b_hh = (const float*)d_in[6];
  float* out = (float*)d_out;

  char* ws = (char*)d_ws;
  __half* gates = (__half*)ws;                           // 78,643,200 B
  float* hfin = (float*)(ws + (size_t)B_ * T_ * G3 * sizeof(__half));
  unsigned int* whh_f =
      (unsigned int*)(ws + (size_t)B_ * T_ * G3 * sizeof(__half)
                      + (size_t)B_ * H_ * sizeof(float));   // 393,216 B
  unsigned int* wih_t = whh_f + (size_t)98304;              // 393,216 B

  pack_whh_frag<<<dim3(384), dim3(256), 0, stream>>>(w_hh, whh_f);
  pack_wiht<<<dim3(384), dim3(256), 0, stream>>>(w_ih, wih_t);
  gates_mfma<<<dim3(400, 3), dim3(512), 0, stream>>>(
      ids, emb, (const __half*)wih_t, b_ih, gates);
  rec_mfma<<<dim3(16), dim3(512), 0, stream>>>(lens, whh_f, b_hh, gates, hfin);
  logits_mfma<<<dim3((NV + 63) / 64), dim3(512), 0, stream>>>(hfin, emb, out);
}

// Round 7
// 505.288 us; speedup vs baseline: 1.4654x; 1.4654x over previous
//
#include <hip/hip_runtime.h>
#include <hip/hip_fp16.h>

#define B_ 256
#define T_ 200
#define H_ 256
#define G3 768            // 3*H
#define NV 50001          // V+1

typedef _Float16 half2v __attribute__((ext_vector_type(2)));
typedef _Float16 half4v __attribute__((ext_vector_type(4)));
typedef _Float16 half8v __attribute__((ext_vector_type(8)));
typedef float f32x4 __attribute__((ext_vector_type(4)));

union U32H2 { unsigned int u; half2v h; };

__device__ __forceinline__ float sigmoidf_(float x) {
  return 1.f / (1.f + __expf(-x));
}
__device__ __forceinline__ float tanhf_(float x) {
  float ax = fabsf(x);
  float e = __expf(-2.f * ax);
  float t = (1.f - e) / (1.f + e);
  return copysignf(t, x);
}
__device__ __forceinline__ f32x4 mfma16(half8v a, half8v b, f32x4 c) {
  return __builtin_amdgcn_mfma_f32_16x16x32_f16(a, b, c, 0, 0, 0);
}

// ---- pack w_hh [256][768] fp32 -> MFMA B-fragment-linear fp16 (verified
// rounds 3/6): frag f = nt*8+kc; half j of lane l of frag (nt,kc) =
// w_hh[kc*32 + (l>>4)*8 + j][nt*16 + (l&15)].
__global__ __launch_bounds__(256) void pack_whh_frag(
    const float* __restrict__ whh, unsigned int* __restrict__ out) {
  int idx = blockIdx.x * 256 + threadIdx.x;   // 0..98303
  int f = idx >> 8;                           // nt*8+kc
  int rem = idx & 255;
  int lane = rem >> 2;
  int jp = rem & 3;
  int nt = f >> 3, kc = f & 7;
  int col = nt * 16 + (lane & 15);
  int k = kc * 32 + (lane >> 4) * 8 + jp * 2;
  U32H2 u;
  u.h.x = (_Float16)whh[(size_t)k * G3 + col];
  u.h.y = (_Float16)whh[(size_t)(k + 1) * G3 + col];
  out[idx] = u.u;
}

// ---- pack w_ih -> transposed fp16 [768 cols][256 k] (gates_mfma B staging).
__global__ __launch_bounds__(256) void pack_wiht(
    const float* __restrict__ wih, unsigned int* __restrict__ out) {
  int idx = blockIdx.x * 256 + threadIdx.x;   // 0..98303
  int col = idx >> 7;
  int kk = (idx & 127) * 2;
  U32H2 u;
  u.h.x = (_Float16)wih[(size_t)kk * G3 + col];
  u.h.y = (_Float16)wih[(size_t)(kk + 1) * G3 + col];
  out[idx] = u.u;
}

// ---- K1: gates = emb[ids] @ w_ih + b_ih via f16 MFMA (round-2, measured).
// Row m = b*T + t; writes gates[m][col] row-major.
__global__ __launch_bounds__(512) void gates_mfma(
    const int* __restrict__ ids, const float* __restrict__ emb,
    const __half* __restrict__ wih_t, const float* __restrict__ b_ih,
    __half* __restrict__ gates) {
  __shared__ __align__(16) _Float16 As[128 * 72];   // [row][k] stride 72
  __shared__ __align__(16) _Float16 Bs[256 * 72];   // [col][k] stride 72
  __shared__ int ids_s[128];
  __shared__ float bs[256];
  const int tid = threadIdx.x;
  const int r0 = blockIdx.x * 128;
  const int c0 = blockIdx.y * 256;
  const int w = tid >> 6, lane = tid & 63;
  const int wm = w >> 2, wn = w & 3;
  const int lr = lane & 15, lk = lane >> 4;

  if (tid < 128) ids_s[tid] = ids[r0 + tid];
  if (tid < 256) bs[tid] = b_ih[c0 + tid];
  __syncthreads();

  f32x4 acc[4][4];
#pragma unroll
  for (int i = 0; i < 4; ++i)
#pragma unroll
    for (int j = 0; j < 4; ++j) acc[i][j] = (f32x4){0.f, 0.f, 0.f, 0.f};

  for (int c = 0; c < 4; ++c) {
    const int kc = c * 64;
#pragma unroll
    for (int r4 = 0; r4 < 4; ++r4) {
      int q = tid + r4 * 512;
      int row = q >> 4;
      int kk = (q & 15) * 4;
      const float4 v = *(const float4*)&emb[(size_t)ids_s[row] * H_ + kc + kk];
      half4v hv = {(_Float16)v.x, (_Float16)v.y, (_Float16)v.z, (_Float16)v.w};
      *(half4v*)&As[row * 72 + kk] = hv;
    }
#pragma unroll
    for (int r4 = 0; r4 < 4; ++r4) {
      int q = tid + r4 * 512;
      int col = q >> 3;
      int cc = q & 7;
      uint4 v = *(const uint4*)((const unsigned short*)wih_t +
                                (size_t)(c0 + col) * H_ + kc + cc * 8);
      *(uint4*)&Bs[col * 72 + cc * 8] = v;
    }
    __syncthreads();
#pragma unroll
    for (int ks = 0; ks < 2; ++ks) {
      half8v af[4], bf[4];
#pragma unroll
      for (int i = 0; i < 4; ++i)
        af[i] = *(const half8v*)&As[(wm * 64 + i * 16 + lr) * 72 + ks * 32 + lk * 8];
#pragma unroll
      for (int j = 0; j < 4; ++j)
        bf[j] = *(const half8v*)&Bs[(wn * 64 + j * 16 + lr) * 72 + ks * 32 + lk * 8];
#pragma unroll
      for (int i = 0; i < 4; ++i)
#pragma unroll
        for (int j = 0; j < 4; ++j)
          acc[i][j] = mfma16(af[i], bf[j], acc[i][j]);
    }
    __syncthreads();
  }
#pragma unroll
  for (int j = 0; j < 4; ++j) {
    const int col = c0 + wn * 64 + j * 16 + lr;
    const float bj = bs[wn * 64 + j * 16 + lr];
#pragma unroll
    for (int i = 0; i < 4; ++i) {
      const int row = r0 + wm * 64 + i * 16 + lk * 4;
#pragma unroll
      for (int r = 0; r < 4; ++r)
        gates[(size_t)(row + r) * G3 + col] = (__half)(acc[i][j][r] + bj);
    }
  }
}

// ---- K2: GRU recurrence via M=1 MFMA. 256 WGs (1 batch row each) x 512 thr.
// Per-CU per-step weight delivery (the measured wall): kc 0..2 resident in
// LDS (147 KB, ~85 B/cy DS pipe), kc 3..7 streamed coalesced uint4 from L2
// (245 KB at measured ~129 B/cy). h is read as MFMA A-fragments: 8 broadcast
// b128 reads/wave/step (vs 1536 cyc of per-thread fdot2 broadcast in r0/r4).
// Wave w owns matched (z,r,h~) col pairs -> in-register GRU update on lanes
// 0-15 (every (lane,reg) of C holds rec[col] since all A rows carry h).
__global__ __launch_bounds__(512) void rec_m1(
    const int* __restrict__ lens, const unsigned int* __restrict__ whh_f,
    const float* __restrict__ b_hh, const __half* __restrict__ gates,
    float* __restrict__ hfin) {
  __shared__ __align__(16) uint4 Wl[144 * 64];        // 147,456 B: kc 0..2
  __shared__ __align__(16) _Float16 hpk[256];         // h state (f16)
  const int tid = threadIdx.x;
  const int b = blockIdx.x;
  const int w = tid >> 6, lane = tid & 63;
  const int lr = lane & 15, lk = lane >> 4;

  const uint4* wf = (const uint4*)whh_f;  // frag (nt,kc): wf[(nt*8+kc)*64+lane]

  // stage kc 0..2 for all 48 nt into LDS slot s = nt*3 + kc (lane-linear)
#pragma unroll
  for (int i = 0; i < 18; ++i) {
    int idx = tid + i * 512;          // 0..9215
    int s = idx >> 6;                 // 0..143
    int l = idx & 63;
    int nt = s / 3, kc = s - 3 * nt;
    Wl[s * 64 + l] = wf[(nt * 8 + kc) * 64 + l];
  }
  if (tid < 128) ((unsigned int*)hpk)[tid] = 0;

  int nt_[6];
#pragma unroll
  for (int p = 0; p < 6; ++p) nt_[p] = (p >> 1) * 16 + w * 2 + (p & 1);

  const int len = lens[b];
  float bhh[6];
  int gcol[6];
#pragma unroll
  for (int p = 0; p < 6; ++p) {
    int col = (p >> 1) * 256 + w * 32 + (p & 1) * 16 + lr;
    bhh[p] = b_hh[col];
    gcol[p] = col;
  }
  float h0 = 0.f, h1 = 0.f;   // h for cols w*32+lr, w*32+16+lr (lanes 0-15)
  __syncthreads();

  const __half* gb = gates + (size_t)b * T_ * G3;
  for (int t = 0; t < len; ++t) {
    // gate inputs for this row/step (lanes 0-15 only); issued first, consumed
    // after the MFMA chain -> HBM latency hidden.
    float gx[6];
    if (lane < 16) {
      const __half* gt = gb + (size_t)t * G3;
#pragma unroll
      for (int p = 0; p < 6; ++p) gx[p] = (float)gt[gcol[p]];
    }
    // stream prefetch: kc 3 and 4 (depth-2)
    uint4 sb[2][6];
#pragma unroll
    for (int p = 0; p < 6; ++p) sb[0][p] = wf[(nt_[p] * 8 + 3) * 64 + lane];
#pragma unroll
    for (int p = 0; p < 6; ++p) sb[1][p] = wf[(nt_[p] * 8 + 4) * 64 + lane];

    f32x4 acc[6];
#pragma unroll
    for (int p = 0; p < 6; ++p) acc[p] = (f32x4){0.f, 0.f, 0.f, 0.f};

    // LDS-resident kc 0..2 (A read: 16 lanes share one address -> broadcast)
#pragma unroll
    for (int kc = 0; kc < 3; ++kc) {
      half8v a = *(const half8v*)&hpk[kc * 32 + lk * 8];
#pragma unroll
      for (int p = 0; p < 6; ++p)
        acc[p] = mfma16(a, __builtin_bit_cast(half8v, Wl[(nt_[p] * 3 + kc) * 64 + lane]),
                        acc[p]);
    }
    // streamed kc 3..7, two-buffer distance-2 pipeline
#pragma unroll
    for (int kc = 3; kc < 8; ++kc) {
      int bi = (kc - 3) & 1;
      half8v a = *(const half8v*)&hpk[kc * 32 + lk * 8];
#pragma unroll
      for (int p = 0; p < 6; ++p)
        acc[p] = mfma16(a, __builtin_bit_cast(half8v, sb[bi][p]), acc[p]);
      if (kc < 6) {
#pragma unroll
        for (int p = 0; p < 6; ++p)
          sb[bi][p] = wf[(nt_[p] * 8 + kc + 2) * 64 + lane];
      }
    }
    // in-register GRU update: every (lane,reg) holds rec[col]; use reg 0.
    if (lane < 16) {
      float z0 = sigmoidf_(gx[0] + acc[0][0] + bhh[0]);
      float z1 = sigmoidf_(gx[1] + acc[1][0] + bhh[1]);
      float r0 = sigmoidf_(gx[2] + acc[2][0] + bhh[2]);
      float r1 = sigmoidf_(gx[3] + acc[3][0] + bhh[3]);
      float q0 = tanhf_(gx[4] + r0 * (acc[4][0] + bhh[4]));
      float q1 = tanhf_(gx[5] + r1 * (acc[5][0] + bhh[5]));
      h0 = z0 * h0 + (1.f - z0) * q0;
      h1 = z1 * h1 + (1.f - z1) * q1;
    }
    __syncthreads();   // all waves done reading hpk
    if (lane < 16) {
      hpk[w * 32 + lr] = (_Float16)h0;
      hpk[w * 32 + 16 + lr] = (_Float16)h1;
    }
    __syncthreads();
  }
  if (lane < 16) {
    hfin[(size_t)b * H_ + w * 32 + lr] = h0;
    hfin[(size_t)b * H_ + w * 32 + 16 + lr] = h1;
  }
}

// ---- K3: logits = hfin @ emb^T via hi/lo-split f16 MFMA (round-2, measured).
__global__ __launch_bounds__(512) void logits_mfma(
    const float* __restrict__ hfin, const float* __restrict__ emb,
    float* __restrict__ out) {
  __shared__ __align__(16) _Float16 As[256 * 72];
  __shared__ __align__(16) _Float16 Bs[64 * 72];
  const int tid = threadIdx.x;
  const int n0 = blockIdx.x * 64;
  const int w = tid >> 6, lane = tid & 63;
  const int wm = w >> 1, wn = w & 1;
  const int lr = lane & 15, lk = lane >> 4;

  f32x4 a1[4][2], a2[4][2];
#pragma unroll
  for (int i = 0; i < 4; ++i)
#pragma unroll
    for (int j = 0; j < 2; ++j) {
      a1[i][j] = (f32x4){0.f, 0.f, 0.f, 0.f};
      a2[i][j] = (f32x4){0.f, 0.f, 0.f, 0.f};
    }

  for (int c = 0; c < 8; ++c) {
    const int kc = c * 32;
#pragma unroll
    for (int r4 = 0; r4 < 4; ++r4) {
      int q = tid + r4 * 512;
      int row = q >> 3;
      int kk = (q & 7) * 4;
      float4 v = *(const float4*)&hfin[(size_t)row * H_ + kc + kk];
      half4v hi = {(_Float16)v.x, (_Float16)v.y, (_Float16)v.z, (_Float16)v.w};
      half4v lo = {(_Float16)((v.x - (float)hi.x) * 1024.f),
                   (_Float16)((v.y - (float)hi.y) * 1024.f),
                   (_Float16)((v.z - (float)hi.z) * 1024.f),
                   (_Float16)((v.w - (float)hi.w) * 1024.f)};
      int base = row * 72 + (kk >> 3) * 16 + (kk & 7);
      *(half4v*)&As[base] = hi;
      *(half4v*)&As[base + 8] = lo;
    }
    {
      int col = tid >> 3;
      int kk = (tid & 7) * 4;
      int n = n0 + col;
      float4 v = (n < NV) ? *(const float4*)&emb[(size_t)n * H_ + kc + kk]
                          : make_float4(0.f, 0.f, 0.f, 0.f);
      half4v hi = {(_Float16)v.x, (_Float16)v.y, (_Float16)v.z, (_Float16)v.w};
      half4v lo = {(_Float16)((v.x - (float)hi.x) * 1024.f),
                   (_Float16)((v.y - (float)hi.y) * 1024.f),
                   (_Float16)((v.z - (float)hi.z) * 1024.f),
                   (_Float16)((v.w - (float)hi.w) * 1024.f)};
      int base = col * 72 + (kk >> 3) * 16 + (kk & 7);
      *(half4v*)&Bs[base] = hi;
      *(half4v*)&Bs[base + 8] = lo;
    }
    __syncthreads();
    half8v ah[4], al[4];
#pragma unroll
    for (int i = 0; i < 4; ++i) {
      int base = (wm * 64 + i * 16 + lr) * 72 + lk * 16;
      ah[i] = *(const half8v*)&As[base];
      al[i] = *(const half8v*)&As[base + 8];
    }
#pragma unroll
    for (int j = 0; j < 2; ++j) {
      int base = (wn * 32 + j * 16 + lr) * 72 + lk * 16;
      half8v bh = *(const half8v*)&Bs[base];
      half8v bl = *(const half8v*)&Bs[base + 8];
#pragma unroll
      for (int i = 0; i < 4; ++i) {
        a1[i][j] = mfma16(ah[i], bh, a1[i][j]);
        a2[i][j] = mfma16(ah[i], bl, a2[i][j]);
        a2[i][j] = mfma16(al[i], bh, a2[i][j]);
      }
    }
    __syncthreads();
  }
#pragma unroll
  for (int j = 0; j < 2; ++j) {
    int n = n0 + wn * 32 + j * 16 + lr;
    if (n < NV) {
#pragma unroll
      for (int i = 0; i < 4; ++i) {
        int row = wm * 64 + i * 16 + lk * 4;
#pragma unroll
        for (int r = 0; r < 4; ++r)
          out[(size_t)(row + r) * NV + n] =
              a1[i][j][r] + a2[i][j][r] * (1.f / 1024.f);
      }
    }
  }
}

extern "C" void kernel_launch(void* const* d_in, const int* in_sizes, int n_in,
                              void* d_out, int out_size, void* d_ws, size_t ws_size,
                              hipStream_t stream) {
  const int* ids = (const int*)d_in[0];
  const int* lens = (const int*)d_in[1];
  const float* emb = (const float*)d_in[2];
  const float* w_ih = (const float*)d_in[3];
  const float* w_hh = (const float*)d_in[4];
  const float* b_ih = (const float*)d_in[5];
  const float* b_hh = (const float*)d_in[6];
  float* out = (float*)d_out;

  char* ws = (char*)d_ws;
  __half* gates = (__half*)ws;                           // 78,643,200 B
  float* hfin = (float*)(ws + (size_t)B_ * T_ * G3 * sizeof(__half));
  unsigned int* whh_f =
      (unsigned int*)(ws + (size_t)B_ * T_ * G3 * sizeof(__half)
                      + (size_t)B_ * H_ * sizeof(float));   // 393,216 B
  unsigned int* wih_t = whh_f + (size_t)98304;              // 393,216 B

  pack_whh_frag<<<dim3(384), dim3(256), 0, stream>>>(w_hh, whh_f);
  pack_wiht<<<dim3(384), dim3(256), 0, stream>>>(w_ih, wih_t);
  gates_mfma<<<dim3(400, 3), dim3(512), 0, stream>>>(
      ids, emb, (const __half*)wih_t, b_ih, gates);
  rec_m1<<<dim3(B_), dim3(512), 0, stream>>>(lens, whh_f, b_hh, gates, hfin);
  logits_mfma<<<dim3((NV + 63) / 64), dim3(512), 0, stream>>>(hfin, emb, out);
}